// Round 22
// baseline (274.377 us; speedup 1.0000x reference)
//
#include <hip/hip_runtime.h>
#include <math.h>

// Problem: x (B=2, C=64, T=16, H=128, W=128) fp32; w (1,2,7,7,7) fp32.
// out = sigmoid(conv3d(concat[max_c(x), mean_c(x)], w, pad=3)) * x
//
// R24 structure: 3-kernel split — the FLOOR PROBE from the decision tree.
// Evidence ledger (measured):
//   - ~160-165 us of the timed region is fixed harness fills; kernels ~100.
//   - pool: 21 us = 6.6 TB/s combined (read-heavy). At floor.
//   - fused K2: conv ~14 us + stream ~63 us. Stream = 4.25 TB/s combined,
//     INVARIANT under: ordering (R12), coalescing (R14), store flavor (R16),
//     block count (R9), chunk depth. All five theories exonerated.
//   - Last untested regime: the stream has only ever run inside a 512-block
//     kernel (2 blocks/CU, phase-aligned behind conv). Fill (6.7 TB/s) and
//     pool (6.6) run at 2048+ blocks / 32 waves/CU.
// Probe: dedicated mul kernel at 4096 blocks, fill-shaped (1 attn load +
// 8 wave-linear load/store pairs per thread). If it reaches copy-class BW
// -> total ~250-258. If it stays ~60 us -> mixed L3-read+HBM-write ceiling
// is real; declare roofline next round.
//   K1 pool:  x (128 MiB) -> pmax|pavg (4 MiB)       [21 us, at floor]
//   K2 conv:  7x7x7 conv + sigmoid -> attn (2 MiB)   [~12-15 us, 512 blk]
//   K3 mul:   out = attn * x, 4096 blocks            [probe: 45-65 us]

#define NP (2 * 16 * 128 * 128) // 524288 pooled points per channel
#define SMH 14                  // halo rows per plane (8 + 6)
#define SMW 134                 // halo cols (128 + 6)
#define SMSTRIDE 136            // row stride (16B-aligned: 136*4 = 544)
#define SMCH (SMH * SMSTRIDE)   // 1904 floats per channel plane

typedef float vfloat4 __attribute__((ext_vector_type(4)));
typedef float vfloat2 __attribute__((ext_vector_type(2)));

// ---------------- Kernel 1: channel max + mean pool (float4) ----------------
__global__ __launch_bounds__(256) void pool_kernel(const float* __restrict__ x,
                                                   float* __restrict__ pmax,
                                                   float* __restrict__ pavg) {
    int j = blockIdx.x * 256 + threadIdx.x; // float4 index in pooled space, [0, 131072)
    int b = j >> 16;                        // 65536 float4 per batch in pooled space
    int rest = j & 65535;
    const float4* x4 = (const float4*)x;
    int base = (b << 22) | rest;            // float4 index into x for c=0

    float4 v = x4[base];
    float4 vmax = v;
    float4 vsum = v;
#pragma unroll 8
    for (int c = 1; c < 64; ++c) {
        float4 u = x4[base + (c << 16)];
        vmax.x = fmaxf(vmax.x, u.x);
        vmax.y = fmaxf(vmax.y, u.y);
        vmax.z = fmaxf(vmax.z, u.z);
        vmax.w = fmaxf(vmax.w, u.w);
        vsum.x += u.x; vsum.y += u.y; vsum.z += u.z; vsum.w += u.w;
    }
    const float s = 1.0f / 64.0f;
    float4 vavg; vavg.x = vsum.x * s; vavg.y = vsum.y * s; vavg.z = vsum.z * s; vavg.w = vsum.w * s;
    ((float4*)pmax)[j] = vmax;
    ((float4*)pavg)[j] = vavg;
}

// ------- Kernel 2: 7x7x7 conv (2ch) + sigmoid -> attn, 8x128 strips --------
// 512 blocks: bid = [b(1) | t(4) | strip(4)]. Thread: ty=tid>>5 (row),
// tx=tid&31 (float4 col). Wave-linear halo staging and attn stores.
__global__ __launch_bounds__(256) void conv_kernel(const float* __restrict__ pooled, // pmax | pavg contiguous
                                                   const float* __restrict__ wgt,    // (1,2,7,7,7)
                                                   float* __restrict__ attn) {
    __shared__ __align__(16) float sm[2 * SMCH]; // 15232 B

    int bid = blockIdx.x;
    int strip = bid & 15;
    int t = (bid >> 4) & 15;
    int b = bid >> 8;
    int th0 = strip << 3;

    int tid = threadIdx.x;
    int ty = tid >> 5;        // 0..7 row within strip
    int tx = tid & 31;        // float4 col 0..31

    float acc0 = 0.f, acc1 = 0.f, acc2 = 0.f, acc3 = 0.f;

    for (int dz = 0; dz < 7; ++dz) {
        int tsrc = t + dz - 3;
        if (tsrc < 0 || tsrc >= 16) continue; // block-uniform: barriers stay uniform

        __syncthreads(); // protect LDS from previous plane's readers
        // Fixed-trip staging: 15 predicated iterations (2*1904 = 3808 slots).
#pragma unroll
        for (int r = 0; r < 15; ++r) {
            int i = tid + (r << 8);
            int ch = i / SMCH;
            int rem = i - ch * SMCH;
            int y = rem / SMSTRIDE;
            int xx = rem - y * SMSTRIDE;
            int gh = th0 + y - 3;
            int gw = xx - 3;
            float val = 0.f;
            if (i < 2 * SMCH && xx < SMW && (unsigned)gh < 128u && (unsigned)gw < 128u)
                val = pooled[ch * NP + (((b << 4) + tsrc) << 14) + (gh << 7) + gw];
            if (i < 2 * SMCH)
                sm[i] = val;
        }
        __syncthreads();

        const float* wdz = wgt + dz * 49;
#pragma unroll
        for (int ch = 0; ch < 2; ++ch) {
#pragma unroll
            for (int dy = 0; dy < 7; ++dy) {
                const float* rp = &sm[ch * SMCH + (ty + dy) * SMSTRIDE + (tx << 2)];
                vfloat4 r0 = *(const vfloat4*)rp;        // 16B-aligned
                vfloat4 r1 = *(const vfloat4*)(rp + 4);
                vfloat2 r2 = *(const vfloat2*)(rp + 8);
                float row[10] = {r0.x, r0.y, r0.z, r0.w,
                                 r1.x, r1.y, r1.z, r1.w,
                                 r2.x, r2.y};
                const float* wr = wdz + ch * 343 + dy * 7;
#pragma unroll
                for (int dx = 0; dx < 7; ++dx) {
                    float wv = wr[dx];
                    acc0 = fmaf(wv, row[dx + 0], acc0);
                    acc1 = fmaf(wv, row[dx + 1], acc1);
                    acc2 = fmaf(wv, row[dx + 2], acc2);
                    acc3 = fmaf(wv, row[dx + 3], acc3);
                }
            }
        }
    }

    vfloat4 av;
    av.x = 1.f / (1.f + __expf(-acc0));
    av.y = 1.f / (1.f + __expf(-acc1));
    av.z = 1.f / (1.f + __expf(-acc2));
    av.w = 1.f / (1.f + __expf(-acc3));

    // attn float4 index over (b,t,h,w/4)
    int aidx = (((b << 4) + t) << 12) + ((th0 + ty) << 5) + tx;
    ((vfloat4*)attn)[aidx] = av;
}

// --------- Kernel 3: out = attn * x — fill-shaped, 4096 blocks --------------
// 1M threads; thread g: s = g&65535 (spatial float4), cg = g>>16 in [0,16):
// b = cg>>3, c0 = (cg&7)*8. One attn load (L2-hot, 2 MiB total), then 8
// channels: batched loads -> batched nt stores, all 1 KiB wave-linear.
// This is structurally identical to the 6.7 TB/s fill / 6.6 TB/s pool.
__global__ __launch_bounds__(256) void mul_kernel(const float* __restrict__ x,
                                                  const float* __restrict__ attn,
                                                  float* __restrict__ out) {
    int g = blockIdx.x * 256 + threadIdx.x; // [0, 1048576)
    int s = g & 65535;                      // spatial float4 index
    int cg = g >> 16;                       // 0..15
    int b = cg >> 3;
    int c0 = (cg & 7) << 3;                 // 0,8,...,56

    const vfloat4* x4 = (const vfloat4*)x;
    const vfloat4* a4 = (const vfloat4*)attn;
    vfloat4* o4 = (vfloat4*)out;

    vfloat4 a = a4[(b << 16) | s];
    int base = (b << 22) | (c0 << 16) | s;

    vfloat4 buf[8];
#pragma unroll
    for (int k = 0; k < 8; ++k)
        buf[k] = x4[base + (k << 16)];
#pragma unroll
    for (int k = 0; k < 8; ++k)
        __builtin_nontemporal_store(buf[k] * a, &o4[base + (k << 16)]);
}

extern "C" void kernel_launch(void* const* d_in, const int* in_sizes, int n_in,
                              void* d_out, int out_size, void* d_ws, size_t ws_size,
                              hipStream_t stream) {
    const float* x = (const float*)d_in[0];
    const float* w = (const float*)d_in[1];
    float* out = (float*)d_out;
    float* ws = (float*)d_ws;

    float* pmax = ws;            // NP floats
    float* pavg = ws + NP;       // NP floats (contiguous: conv indexes ch*NP)
    float* attn = ws + 2 * NP;   // NP floats (2 MiB) — ws is >= 6 MiB
                                 // (R4's split path ran & passed with same layout)

    pool_kernel<<<NP / 4 / 256, 256, 0, stream>>>(x, pmax, pavg);
    conv_kernel<<<2 * 16 * 16, 256, 0, stream>>>(pmax, w, attn);
    mul_kernel<<<4096, 256, 0, stream>>>(x, attn, out);
}